// Round 7
// baseline (309.352 us; speedup 1.0000x reference)
//
#include <hip/hip_runtime.h>

#define NF    256   // IN_F
#define HD    256   // H*D
#define NH    4
#define DH    64
#define WINS  128   // WIN
#define HALFW 64
#define TOPK  32
#define GROWS 16    // rows per gemm block
#define KCH   64    // gemm k-chunk staged in LDS
#define NB    4     // nodes per attn block
#define UMAX  132   // max union window (131) rounded up

// ---- fused Q/K projection + output zero-fill tail ----
// grid (n/GROWS, 2): y==0 -> Q, y==1 -> K (both row-major). 256 threads,
// thread t owns output column t for 16 rows. W staged in LDS by 64-k chunks
// (conflict-free lw[k][t] reads); X via wave-uniform s_loads. After compute,
// each block streams a 128KB zero slice of out (no barrier -> drains overlap
// other blocks' compute).
__global__ __launch_bounds__(256) void qk_gemm_fill_kernel(
    const float* __restrict__ X,
    const float* __restrict__ Wq, const float* __restrict__ bq,
    const float* __restrict__ Wk, const float* __restrict__ bk,
    float* __restrict__ Qb, float* __restrict__ Kb,
    float4* __restrict__ outz, int total4, int per_block, int n)
{
    __shared__ float lw[KCH * HD];          // 64 KB
    const int t = threadIdx.x;
    const bool isK = (blockIdx.y != 0);
    const float* W   = isK ? Wk : Wq;
    const float* bia = isK ? bk : bq;
    float*       Out = isK ? Kb : Qb;

    const int rowBase = __builtin_amdgcn_readfirstlane(blockIdx.x * GROWS);
    const float* Xs = X + (size_t)rowBase * NF;   // scalar base -> s_load

    float acc[GROWS];
#pragma unroll
    for (int r = 0; r < GROWS; ++r) acc[r] = 0.f;

    for (int k0 = 0; k0 < NF; k0 += KCH) {
        __syncthreads();                    // previous chunk fully consumed
        {   // stage W[k0..k0+63][0..255]: 4096 float4s, 16/thread, coalesced
            const float4* wsrc = (const float4*)(W + (size_t)k0 * HD);
            float4* ldst = (float4*)lw;
#pragma unroll
            for (int j = 0; j < (KCH * HD / 4) / 256; ++j)
                ldst[j * 256 + t] = wsrc[j * 256 + t];
        }
        __syncthreads();
#pragma unroll 8
        for (int kk = 0; kk < KCH; kk += 4) {
            float w0 = lw[(kk + 0) * HD + t];
            float w1 = lw[(kk + 1) * HD + t];
            float w2 = lw[(kk + 2) * HD + t];
            float w3 = lw[(kk + 3) * HD + t];
#pragma unroll
            for (int r = 0; r < GROWS; ++r) {
                float4 xv = *(const float4*)(Xs + r * NF + k0 + kk); // uniform
                acc[r] += xv.x * w0 + xv.y * w1 + xv.z * w2 + xv.w * w3;
            }
        }
    }

    const float bv = bia[t];
#pragma unroll
    for (int r = 0; r < GROWS; ++r)
        Out[(size_t)(rowBase + r) * HD + t] = acc[r] + bv;

    // barrier-free zero-fill tail: this block's slice of out
    const int bflat = blockIdx.y * gridDim.x + blockIdx.x;
    const size_t base = (size_t)bflat * per_block;
    const float4 z = make_float4(0.f, 0.f, 0.f, 0.f);
    for (int j = t; j < per_block; j += 256) {
        size_t g = base + j;
        if (g < (size_t)total4) outz[g] = z;
    }
}

// ---- attention: block = 4 nodes, 4 waves. Wave loads full 1KB K-rows of the
// union window (lane l -> dims 4l..4l+3, head = l>>4); per-node dots via
// 16-lane shfl reduce; ONE barrier; per-(node,head) softmax with closed-form
// zero-pad handling; rank-count top-32; sparse scatter of 1.0s. ----
__global__ __launch_bounds__(256) void attn_topk_kernel(
    const float* __restrict__ Q,
    const float* __restrict__ K,
    const int* __restrict__ nnpg, int n_graphs,
    const int* __restrict__ nrel,
    float* __restrict__ out, int n)
{
    const int t    = threadIdx.x;
    const int wave = t >> 6;
    const int lane = t & 63;
    const int i0   = blockIdx.x * NB;

    __shared__ float sc[NB][NH][UMAX];      // scores in union coords
    __shared__ float attnv[NB][WINS];       // head-mean in slot coords

    // per-node segment bounds: tile(nnpg, R) -> cumsum -> searchsorted(right)
    int st[NB], en[NB];
    {
        int R = nrel[0];
        int total = n_graphs * R;
#pragma unroll
        for (int nn = 0; nn < NB; ++nn) {
            int i = i0 + nn, ss = 0, se = n, cum = 0;
            for (int e = 0; e < total; ++e) {
                int sz = nnpg[e % n_graphs];
                int nc = cum + sz;
                if (i >= cum && i < nc) { ss = cum; se = nc; }
                cum = nc;
            }
            st[nn] = max(ss, i - HALFW);
            en[nn] = min(se, i + HALFW);
        }
    }
    const int u0 = st[0];                   // st/en monotone in i
    const int U  = en[NB - 1] - u0;         // <= 131

    // q fragments: q4[nn] = Q[i0+nn][4*lane .. 4*lane+3]
    float4 q4[NB];
#pragma unroll
    for (int nn = 0; nn < NB; ++nn)
        q4[nn] = *(const float4*)(Q + (size_t)(i0 + nn) * HD + 4 * lane);

    const int h = lane >> 4;

    // score phase: wave w handles union rows w, w+4, ...
    for (int r = wave; r < U; r += 4) {
        float4 k4 = *(const float4*)(K + (size_t)(u0 + r) * HD + 4 * lane);
#pragma unroll
        for (int nn = 0; nn < NB; ++nn) {
            float d = q4[nn].x * k4.x + q4[nn].y * k4.y +
                      q4[nn].z * k4.z + q4[nn].w * k4.w;
            d += __shfl_xor(d, 1);
            d += __shfl_xor(d, 2);
            d += __shfl_xor(d, 4);
            d += __shfl_xor(d, 8);
            if ((lane & 15) == 0) sc[nn][h][r] = d * 0.25f;  // /sqrt(64)/tau
        }
    }
    __syncthreads();

    // from here: wave nn owns node nn; everything wave-local
    const int nn = wave;
    int stn = st[0], enn = en[0];
    if (nn == 1) { stn = st[1]; enn = en[1]; }
    if (nn == 2) { stn = st[2]; enn = en[2]; }
    if (nn == 3) { stn = st[3]; enn = en[3]; }
    const int off = stn - u0;
    const int win = enn - stn;              // 64..128

    float mean0 = 0.f, mean1 = 0.f;
#pragma unroll
    for (int hh = 0; hh < NH; ++hh) {
        float s0 = (lane      < win) ? sc[nn][hh][off + lane]      : -1e30f;
        float s1 = (lane + 64 < win) ? sc[nn][hh][off + lane + 64] : -1e30f;
        float m = fmaxf(s0, s1);
#pragma unroll
        for (int o = 32; o > 0; o >>= 1) m = fmaxf(m, __shfl_xor(m, o));
        if (win < WINS) m = fmaxf(m, 0.f);  // zero-score pad slots
        float e0 = (lane      < win) ? expf(s0 - m) : 0.f;
        float e1 = (lane + 64 < win) ? expf(s1 - m) : 0.f;
        float ssum = e0 + e1;
#pragma unroll
        for (int o = 32; o > 0; o >>= 1) ssum += __shfl_xor(ssum, o);
        ssum += (float)(WINS - win) * expf(-m);   // pad contributions
        float inv = 1.f / ssum;
        mean0 += e0 * inv;
        mean1 += e1 * inv;
    }
    const float w0v = (lane      < win) ? mean0 * 0.25f : -1.0f;
    const float w1v = (lane + 64 < win) ? mean1 * 0.25f : -1.0f;
    attnv[nn][lane]      = w0v;
    attnv[nn][lane + 64] = w1v;             // wave-private slab, no barrier

    // stable top-32 rank count (lower slot wins ties, like lax.top_k)
    int cnt0 = 0, cnt1 = 0;
    const int s0i = lane, s1i = lane + 64;
#pragma unroll
    for (int j4 = 0; j4 < WINS / 4; ++j4) {
        float4 a4 = *(const float4*)&attnv[nn][j4 * 4];  // broadcast b128
        int jb = j4 * 4;
        cnt0 += (a4.x > w0v) || (a4.x == w0v && (jb + 0) < s0i);
        cnt0 += (a4.y > w0v) || (a4.y == w0v && (jb + 1) < s0i);
        cnt0 += (a4.z > w0v) || (a4.z == w0v && (jb + 2) < s0i);
        cnt0 += (a4.w > w0v) || (a4.w == w0v && (jb + 3) < s0i);
        cnt1 += (a4.x > w1v) || (a4.x == w1v && (jb + 0) < s1i);
        cnt1 += (a4.y > w1v) || (a4.y == w1v && (jb + 1) < s1i);
        cnt1 += (a4.z > w1v) || (a4.z == w1v && (jb + 2) < s1i);
        cnt1 += (a4.w > w1v) || (a4.w == w1v && (jb + 3) < s1i);
    }

    float* orow = out + (size_t)(i0 + nn) * n;
    if (s0i < win && cnt0 < TOPK) orow[stn + s0i] = 1.0f;
    if (s1i < win && cnt1 < TOPK) orow[stn + s1i] = 1.0f;
}

extern "C" void kernel_launch(void* const* d_in, const int* in_sizes, int n_in,
                              void* d_out, int out_size, void* d_ws, size_t ws_size,
                              hipStream_t stream)
{
    const float* X  = (const float*)d_in[0];
    const float* Wq = (const float*)d_in[1];
    const float* bq = (const float*)d_in[2];
    const float* Wk = (const float*)d_in[3];
    const float* bk = (const float*)d_in[4];
    const int* nnpg = (const int*)d_in[5];
    const int* nrel = (const int*)d_in[6];

    const int n = in_sizes[0] / NF;
    const int n_graphs = in_sizes[5];

    float* Qb = (float*)d_ws;                 // [n][256]
    float* Kb = Qb + (size_t)n * HD;          // [n][256]
    float* out = (float*)d_out;

    const int gx = n / GROWS;                 // 256
    const int nblocks = gx * 2;               // 512
    const int total4 = out_size >> 2;
    const int per_block = (total4 + nblocks - 1) / nblocks;

    dim3 gg(gx, 2);
    qk_gemm_fill_kernel<<<gg, 256, 0, stream>>>(X, Wq, bq, Wk, bk, Qb, Kb,
                                                (float4*)out, total4, per_block, n);

    attn_topk_kernel<<<n / NB, 256, 0, stream>>>(Qb, Kb, nnpg, n_graphs, nrel, out, n);
}

// Round 8
// 188.835 us; speedup vs baseline: 1.6382x; 1.6382x over previous
//
#include <hip/hip_runtime.h>

#define NF    256   // IN_F
#define HD    256   // H*D
#define NH    4
#define DH    64
#define WINS  128   // WIN
#define HALFW 64
#define TOPK  32
#define GROWS 16    // rows per gemm block (4 waves x 4 rows)
#define NB    4     // nodes per attn block
#define UMAX  132   // max union window (131) rounded up

// ------------- fused Q/K projection: X[n,256] @ W[256,256] + b -------------
// grid (n/16, 2). Wave = 4 rows; lane owns cols 4l..4l+3. Per k-group of 8:
// 8 independent b128 W loads (full 1KB row per instr) + X via wave-uniform
// s_loads. Row-major coalesced stores for BOTH Q and K.
__global__ __launch_bounds__(256) void qk_gemm_kernel(
    const float* __restrict__ X,
    const float* __restrict__ Wq, const float* __restrict__ bq,
    const float* __restrict__ Wk, const float* __restrict__ bk,
    float* __restrict__ Qb, float* __restrict__ Kb, int n)
{
    const int t    = threadIdx.x;
    const int wave = t >> 6;
    const int lane = t & 63;
    const bool isK = (blockIdx.y != 0);
    const float* W   = isK ? Wk : Wq;
    const float* bia = isK ? bk : bq;
    float*       Out = isK ? Kb : Qb;

    const int r0  = blockIdx.x * GROWS + wave * 4;
    const int r0s = __builtin_amdgcn_readfirstlane(r0);
    const float* Xs = X + (size_t)r0s * NF;        // scalar base -> s_load

    float4 acc[4];
#pragma unroll
    for (int r = 0; r < 4; ++r) acc[r] = make_float4(0.f, 0.f, 0.f, 0.f);

    for (int k = 0; k < NF; k += 8) {
        float4 wv[8];
#pragma unroll
        for (int u = 0; u < 8; ++u)                 // 8 independent b128 loads
            wv[u] = *(const float4*)(W + (size_t)(k + u) * HD + 4 * lane);
        float4 xv[4][2];
#pragma unroll
        for (int r = 0; r < 4; ++r) {               // wave-uniform s_loads
            xv[r][0] = *(const float4*)(Xs + r * NF + k);
            xv[r][1] = *(const float4*)(Xs + r * NF + k + 4);
        }
#pragma unroll
        for (int u = 0; u < 8; ++u) {
#pragma unroll
            for (int r = 0; r < 4; ++r) {
                float4 x4 = xv[r][u >> 2];
                float xk = (u & 3) == 0 ? x4.x : (u & 3) == 1 ? x4.y
                         : (u & 3) == 2 ? x4.z : x4.w;
                acc[r].x += xk * wv[u].x;
                acc[r].y += xk * wv[u].y;
                acc[r].z += xk * wv[u].z;
                acc[r].w += xk * wv[u].w;
            }
        }
    }

    const float4 bv = *(const float4*)(bia + 4 * lane);
#pragma unroll
    for (int r = 0; r < 4; ++r) {
        acc[r].x += bv.x; acc[r].y += bv.y; acc[r].z += bv.z; acc[r].w += bv.w;
        *(float4*)(Out + (size_t)(r0 + r) * HD + 4 * lane) = acc[r];  // coalesced
    }
}

// ---------------------- streaming zero-fill of output ----------------------
__global__ __launch_bounds__(256) void fill_zero_kernel(float4* __restrict__ p, int n4)
{
    int idx = blockIdx.x * 256 + threadIdx.x;
    int stride = gridDim.x * 256;
    float4 z = make_float4(0.f, 0.f, 0.f, 0.f);
    for (int c = idx; c < n4; c += stride) p[c] = z;
}

// ---- attention: block = 4 nodes, 4 waves. Wave loads full 1KB K-rows of the
// union window in 12-deep independent batches (lane l -> dims 4l..4l+3,
// head = l>>4); per-node dots via 16-lane shfl; one barrier; softmax with
// closed-form zero-pad handling; rank-count top-32; sparse scatter. ----
__global__ __launch_bounds__(256) void attn_topk_kernel(
    const float* __restrict__ Q,
    const float* __restrict__ K,
    const int* __restrict__ nnpg, int n_graphs,
    const int* __restrict__ nrel,
    float* __restrict__ out, int n)
{
    const int t    = threadIdx.x;
    const int wave = t >> 6;
    const int lane = t & 63;
    const int i0   = blockIdx.x * NB;

    __shared__ float sc[NB][NH][UMAX];      // scores in union coords
    __shared__ float attnv[NB][WINS];       // head-mean in slot coords

    // per-node segment bounds: tile(nnpg, R) -> cumsum -> searchsorted(right)
    int st[NB], en[NB];
    {
        int R = nrel[0];
        int total = n_graphs * R;
#pragma unroll
        for (int nn = 0; nn < NB; ++nn) {
            int i = i0 + nn, ss = 0, se = n, cum = 0;
            for (int e = 0; e < total; ++e) {
                int sz = nnpg[e % n_graphs];
                int nc = cum + sz;
                if (i >= cum && i < nc) { ss = cum; se = nc; }
                cum = nc;
            }
            st[nn] = max(ss, i - HALFW);
            en[nn] = min(se, i + HALFW);
        }
    }
    const int u0 = st[0];                   // st/en monotone in i
    const int U  = en[NB - 1] - u0;         // 64..131

    // q fragments: q4[nn] = Q[i0+nn][4*lane .. 4*lane+3]
    float4 q4[NB];
#pragma unroll
    for (int nn = 0; nn < NB; ++nn)
        q4[nn] = *(const float4*)(Q + (size_t)(i0 + nn) * HD + 4 * lane);

    const int h = lane >> 4;

    // score phase: wave w covers union rows {w+4j}; fixed trip count with
    // row clamping so the 12-deep load batch is fully unrolled/independent.
    for (int j0 = 0; j0 < 33; j0 += 12) {
        float4 kv[12];
        int rows[12];
#pragma unroll
        for (int u = 0; u < 12; ++u) {
            int r = wave + 4 * (j0 + u);
            rows[u] = r;
            int rc = min(r, U - 1);                       // clamp: always valid
            kv[u] = *(const float4*)(K + (size_t)(u0 + rc) * HD + 4 * lane);
        }
#pragma unroll
        for (int u = 0; u < 12; ++u) {
#pragma unroll
            for (int nn = 0; nn < NB; ++nn) {
                float d = q4[nn].x * kv[u].x + q4[nn].y * kv[u].y +
                          q4[nn].z * kv[u].z + q4[nn].w * kv[u].w;
                d += __shfl_xor(d, 1);
                d += __shfl_xor(d, 2);
                d += __shfl_xor(d, 4);
                d += __shfl_xor(d, 8);
                if ((lane & 15) == 0 && rows[u] < U)
                    sc[nn][h][rows[u]] = d * 0.25f;       // /sqrt(64)/tau
            }
        }
    }
    __syncthreads();

    // from here: wave nn owns node nn; everything wave-local
    const int nn = wave;
    int stn = st[0], enn = en[0];
    if (nn == 1) { stn = st[1]; enn = en[1]; }
    if (nn == 2) { stn = st[2]; enn = en[2]; }
    if (nn == 3) { stn = st[3]; enn = en[3]; }
    const int off = stn - u0;
    const int win = enn - stn;              // 64..128

    float mean0 = 0.f, mean1 = 0.f;
#pragma unroll
    for (int hh = 0; hh < NH; ++hh) {
        float s0 = (lane      < win) ? sc[nn][hh][off + lane]      : -1e30f;
        float s1 = (lane + 64 < win) ? sc[nn][hh][off + lane + 64] : -1e30f;
        float m = fmaxf(s0, s1);
#pragma unroll
        for (int o = 32; o > 0; o >>= 1) m = fmaxf(m, __shfl_xor(m, o));
        if (win < WINS) m = fmaxf(m, 0.f);  // zero-score pad slots
        float e0 = (lane      < win) ? expf(s0 - m) : 0.f;
        float e1 = (lane + 64 < win) ? expf(s1 - m) : 0.f;
        float ssum = e0 + e1;
#pragma unroll
        for (int o = 32; o > 0; o >>= 1) ssum += __shfl_xor(ssum, o);
        ssum += (float)(WINS - win) * expf(-m);   // pad contributions
        float inv = 1.f / ssum;
        mean0 += e0 * inv;
        mean1 += e1 * inv;
    }
    const float w0v = (lane      < win) ? mean0 * 0.25f : -1.0f;
    const float w1v = (lane + 64 < win) ? mean1 * 0.25f : -1.0f;
    attnv[nn][lane]      = w0v;
    attnv[nn][lane + 64] = w1v;             // wave-private slab, no barrier

    // stable top-32 rank count (lower slot wins ties, like lax.top_k)
    int cnt0 = 0, cnt1 = 0;
    const int s0i = lane, s1i = lane + 64;
#pragma unroll
    for (int j4 = 0; j4 < WINS / 4; ++j4) {
        float4 a4 = *(const float4*)&attnv[nn][j4 * 4];  // broadcast b128
        int jb = j4 * 4;
        cnt0 += (a4.x > w0v) || (a4.x == w0v && (jb + 0) < s0i);
        cnt0 += (a4.y > w0v) || (a4.y == w0v && (jb + 1) < s0i);
        cnt0 += (a4.z > w0v) || (a4.z == w0v && (jb + 2) < s0i);
        cnt0 += (a4.w > w0v) || (a4.w == w0v && (jb + 3) < s0i);
        cnt1 += (a4.x > w1v) || (a4.x == w1v && (jb + 0) < s1i);
        cnt1 += (a4.y > w1v) || (a4.y == w1v && (jb + 1) < s1i);
        cnt1 += (a4.z > w1v) || (a4.z == w1v && (jb + 2) < s1i);
        cnt1 += (a4.w > w1v) || (a4.w == w1v && (jb + 3) < s1i);
    }

    float* orow = out + (size_t)(i0 + nn) * n;
    if (s0i < win && cnt0 < TOPK) orow[stn + s0i] = 1.0f;
    if (s1i < win && cnt1 < TOPK) orow[stn + s1i] = 1.0f;
}

extern "C" void kernel_launch(void* const* d_in, const int* in_sizes, int n_in,
                              void* d_out, int out_size, void* d_ws, size_t ws_size,
                              hipStream_t stream)
{
    const float* X  = (const float*)d_in[0];
    const float* Wq = (const float*)d_in[1];
    const float* bq = (const float*)d_in[2];
    const float* Wk = (const float*)d_in[3];
    const float* bk = (const float*)d_in[4];
    const int* nnpg = (const int*)d_in[5];
    const int* nrel = (const int*)d_in[6];

    const int n = in_sizes[0] / NF;
    const int n_graphs = in_sizes[5];

    float* Qb = (float*)d_ws;                 // [n][256]
    float* Kb = Qb + (size_t)n * HD;          // [n][256]
    float* out = (float*)d_out;

    dim3 gg(n / GROWS, 2);
    qk_gemm_kernel<<<gg, 256, 0, stream>>>(X, Wq, bq, Wk, bk, Qb, Kb, n);

    fill_zero_kernel<<<4096, 256, 0, stream>>>((float4*)out, out_size >> 2);

    attn_topk_kernel<<<n / NB, 256, 0, stream>>>(Qb, Kb, nnpg, n_graphs, nrel, out, n);
}

// Round 9
// 183.393 us; speedup vs baseline: 1.6868x; 1.0297x over previous
//
#include <hip/hip_runtime.h>

#define NF    256   // IN_F
#define HD    256   // H*D
#define NH    4
#define DH    64
#define WINS  128   // WIN
#define HALFW 64
#define TOPK  32
#define GROWS 16    // rows per gemm block (4 waves x 4 rows)
#define KCH   16    // k-chunk staged in LDS (16 KB)
#define NCH   (NF / KCH)
#define NB    4     // nodes per attn block

__device__ __forceinline__ float readlane_f(float v, int l) {
    return __uint_as_float(__builtin_amdgcn_readlane(__float_as_uint(v), l));
}
__device__ __forceinline__ float getc(const float4& v, int j) {
    return j == 0 ? v.x : j == 1 ? v.y : j == 2 ? v.z : v.w;
}

// ------------- fused Q/K projection: X[n,256] @ W[256,256] + b -------------
// grid (n/16, 2): y==0 -> Q row-major; y==1 -> K transposed (Kt[col][node]).
// W staged in LDS in 16KB chunks, double-buffered (one barrier/chunk), shared
// by all 8... 4 waves -> W global traffic cut 4x vs per-wave streaming.
// Wave = 4 rows; lane owns cols 4l..4l+3. X via wave-uniform broadcast loads.
__global__ __launch_bounds__(256) void qk_gemm_kernel(
    const float* __restrict__ X,
    const float* __restrict__ Wq, const float* __restrict__ bq,
    const float* __restrict__ Wk, const float* __restrict__ bk,
    float* __restrict__ Qb, float* __restrict__ Kt, int n)
{
    __shared__ float lw[2][KCH][HD];        // 2 x 16 KB
    const int t    = threadIdx.x;
    const int wave = t >> 6;
    const int lane = t & 63;
    const bool isK = (blockIdx.y != 0);
    const float* W   = isK ? Wk : Wq;
    const float* bia = isK ? bk : bq;

    const int r0 = blockIdx.x * GROWS + wave * 4;
    const float* Xw = X + (size_t)r0 * NF;  // wave-uniform -> broadcast loads

    float4 acc[4];
#pragma unroll
    for (int r = 0; r < 4; ++r) acc[r] = make_float4(0.f, 0.f, 0.f, 0.f);

    {   // prologue: stage chunk 0 (4 coalesced b128 per thread)
        const float4* wsrc = (const float4*)W;
        float4* dst = (float4*)&lw[0][0][0];
#pragma unroll
        for (int j = 0; j < 4; ++j) dst[j * 256 + t] = wsrc[j * 256 + t];
    }

    for (int c = 0; c < NCH; ++c) {
        float4 pf[4];
        const bool more = (c + 1 < NCH);
        if (more) {                          // prefetch next chunk into regs
            const float4* wsrc = (const float4*)(W + (size_t)(c + 1) * KCH * HD);
#pragma unroll
            for (int j = 0; j < 4; ++j) pf[j] = wsrc[j * 256 + t];
        }
        __syncthreads();                     // lw[c&1] staged & prior reads done
        const float (*lwc)[HD] = lw[c & 1];

#pragma unroll
        for (int kk = 0; kk < KCH; kk += 4) {
            float4 wv0 = *(const float4*)&lwc[kk + 0][4 * lane];
            float4 wv1 = *(const float4*)&lwc[kk + 1][4 * lane];
            float4 wv2 = *(const float4*)&lwc[kk + 2][4 * lane];
            float4 wv3 = *(const float4*)&lwc[kk + 3][4 * lane];
#pragma unroll
            for (int r = 0; r < 4; ++r) {
                float4 xv = *(const float4*)(Xw + r * NF + c * KCH + kk);
                acc[r].x += xv.x * wv0.x + xv.y * wv1.x + xv.z * wv2.x + xv.w * wv3.x;
                acc[r].y += xv.x * wv0.y + xv.y * wv1.y + xv.z * wv2.y + xv.w * wv3.y;
                acc[r].z += xv.x * wv0.z + xv.y * wv1.z + xv.z * wv2.z + xv.w * wv3.z;
                acc[r].w += xv.x * wv0.w + xv.y * wv1.w + xv.z * wv2.w + xv.w * wv3.w;
            }
        }
        if (more) {                          // publish prefetched chunk
            float4* dst = (float4*)&lw[(c + 1) & 1][0][0];
#pragma unroll
            for (int j = 0; j < 4; ++j) dst[j * 256 + t] = pf[j];
        }
    }

    const float4 bv = *(const float4*)(bia + 4 * lane);
#pragma unroll
    for (int r = 0; r < 4; ++r) {
        acc[r].x += bv.x; acc[r].y += bv.y; acc[r].z += bv.z; acc[r].w += bv.w;
    }

    if (!isK) {
#pragma unroll
        for (int r = 0; r < 4; ++r)
            *(float4*)(Qb + (size_t)(r0 + r) * HD + 4 * lane) = acc[r];
    } else {
#pragma unroll
        for (int j = 0; j < 4; ++j) {
            int col = 4 * lane + j;
            *(float4*)(Kt + (size_t)col * n + r0) =
                make_float4(getc(acc[0], j), getc(acc[1], j),
                            getc(acc[2], j), getc(acc[3], j));
        }
    }
}

// ---------------------- streaming zero-fill of output ----------------------
__global__ __launch_bounds__(256) void fill_zero_kernel(float4* __restrict__ p, int n4)
{
    int idx = blockIdx.x * 256 + threadIdx.x;
    int stride = gridDim.x * 256;
    float4 z = make_float4(0.f, 0.f, 0.f, 0.f);
    for (int c = idx; c < n4; c += stride) p[c] = z;
}

// ---- attention (R6 version, best measured): block = NB=4 nodes, wave = head.
// Lane owns union cols 4l..4l+3 (float4 KT loads, each value reused by 4
// nodes). Softmax with closed-form zero-pad handling; rank-count top-32. ----
__global__ __launch_bounds__(256) void attn_topk_kernel(
    const float* __restrict__ Q,
    const float* __restrict__ KT,
    const int* __restrict__ nnpg, int n_graphs,
    const int* __restrict__ nrel,
    float* __restrict__ out, int n)
{
    const int t    = threadIdx.x;
    const int wave = t >> 6;
    const int lane = t & 63;
    const int i0   = blockIdx.x * NB;

    __shared__ float pslab[NH][NB][WINS];   // per-head probs in slot space
    __shared__ float attnv[NB][WINS];

    int st[NB], en[NB];
    {
        int R = nrel[0];
        int total = n_graphs * R;
#pragma unroll
        for (int nn = 0; nn < NB; ++nn) {
            int i = i0 + nn, ss = 0, se = n, cum = 0;
            for (int e = 0; e < total; ++e) {
                int sz = nnpg[e % n_graphs];
                int nc = cum + sz;
                if (i >= cum && i < nc) { ss = cum; se = nc; }
                cum = nc;
            }
            st[nn] = max(ss, i - HALFW);
            en[nn] = min(se, i + HALFW);
        }
    }
    const int u0 = (min(min(st[0], st[1]), min(st[2], st[3]))) & ~3;  // b128 align
    const int Ue = max(max(en[0], en[1]), max(en[2], en[3]));
    const int U  = Ue - u0;                       // <= 134 -> <= 34 active lanes

    float qreg[NB];
#pragma unroll
    for (int nn = 0; nn < NB; ++nn)
        qreg[nn] = Q[(size_t)(i0 + nn) * HD + wave * DH + lane];

    float4 acc[NB];
#pragma unroll
    for (int nn = 0; nn < NB; ++nn) acc[nn] = make_float4(0.f, 0.f, 0.f, 0.f);

    const bool act = (4 * lane < U);
    const float* kb = KT + (size_t)(wave * DH) * n + u0 + 4 * lane;

    for (int d0 = 0; d0 < DH; d0 += 8) {
        float4 kv[8];
#pragma unroll
        for (int u = 0; u < 8; ++u)
            kv[u] = act ? *(const float4*)(kb + (size_t)(d0 + u) * n)
                        : make_float4(0.f, 0.f, 0.f, 0.f);
#pragma unroll
        for (int u = 0; u < 8; ++u) {
#pragma unroll
            for (int nn = 0; nn < NB; ++nn) {
                float qd = readlane_f(qreg[nn], d0 + u);
                acc[nn].x += qd * kv[u].x;
                acc[nn].y += qd * kv[u].y;
                acc[nn].z += qd * kv[u].z;
                acc[nn].w += qd * kv[u].w;
            }
        }
    }

#pragma unroll
    for (int nn = 0; nn < NB; ++nn) {
        const int rs  = st[nn] - u0;
        const int re  = en[nn] - u0;
        const int win = en[nn] - st[nn];
        float s[4]; bool v[4];
#pragma unroll
        for (int j = 0; j < 4; ++j) {
            int c = 4 * lane + j;
            v[j] = (c >= rs) && (c < re);
            s[j] = getc(acc[nn], j) * 0.25f;      // /sqrt(64)/tau
        }
        float lm = -1e30f;
#pragma unroll
        for (int j = 0; j < 4; ++j) if (v[j]) lm = fmaxf(lm, s[j]);
#pragma unroll
        for (int off = 32; off > 0; off >>= 1) lm = fmaxf(lm, __shfl_xor(lm, off));
        if (win < WINS) lm = fmaxf(lm, 0.f);      // pad slots have score 0
        float p[4], ls = 0.f;
#pragma unroll
        for (int j = 0; j < 4; ++j) {
            p[j] = v[j] ? expf(s[j] - lm) : 0.f;
            ls += p[j];
        }
#pragma unroll
        for (int off = 32; off > 0; off >>= 1) ls += __shfl_xor(ls, off);
        ls += (float)(WINS - win) * expf(-lm);    // pad contributions
        float inv = 1.f / ls;
#pragma unroll
        for (int j = 0; j < 4; ++j) {
            int c = 4 * lane + j;
            if (v[j]) pslab[wave][nn][c - rs] = p[j] * inv;
        }
    }
    __syncthreads();

    {
        const int nn = wave;
        int stn = st[0], enn = en[0];
        if (nn == 1) { stn = st[1]; enn = en[1]; }
        if (nn == 2) { stn = st[2]; enn = en[2]; }
        if (nn == 3) { stn = st[3]; enn = en[3]; }
        const int win = enn - stn;

        float a0 = (lane < win)
            ? 0.25f * (pslab[0][nn][lane] + pslab[1][nn][lane] +
                       pslab[2][nn][lane] + pslab[3][nn][lane]) : -1.0f;
        float a1 = (lane + 64 < win)
            ? 0.25f * (pslab[0][nn][lane + 64] + pslab[1][nn][lane + 64] +
                       pslab[2][nn][lane + 64] + pslab[3][nn][lane + 64]) : -1.0f;
        attnv[nn][lane]      = a0;
        attnv[nn][lane + 64] = a1;
    }
    __syncthreads();

    {
        const int nn = wave;
        int stn = st[0], enn = en[0];
        if (nn == 1) { stn = st[1]; enn = en[1]; }
        if (nn == 2) { stn = st[2]; enn = en[2]; }
        if (nn == 3) { stn = st[3]; enn = en[3]; }
        const int win = enn - stn;

        const float w0v = attnv[nn][lane];
        const float w1v = attnv[nn][lane + 64];
        const int s0 = lane, s1 = lane + 64;
        int cnt0 = 0, cnt1 = 0;
#pragma unroll
        for (int j4 = 0; j4 < WINS / 4; ++j4) {
            float4 a4 = *(const float4*)&attnv[nn][j4 * 4];   // broadcast b128
            int jb = j4 * 4;
            cnt0 += (a4.x > w0v) || (a4.x == w0v && (jb + 0) < s0);
            cnt0 += (a4.y > w0v) || (a4.y == w0v && (jb + 1) < s0);
            cnt0 += (a4.z > w0v) || (a4.z == w0v && (jb + 2) < s0);
            cnt0 += (a4.w > w0v) || (a4.w == w0v && (jb + 3) < s0);
            cnt1 += (a4.x > w1v) || (a4.x == w1v && (jb + 0) < s1);
            cnt1 += (a4.y > w1v) || (a4.y == w1v && (jb + 1) < s1);
            cnt1 += (a4.z > w1v) || (a4.z == w1v && (jb + 2) < s1);
            cnt1 += (a4.w > w1v) || (a4.w == w1v && (jb + 3) < s1);
        }
        float* orow = out + (size_t)(i0 + nn) * n;
        if (s0 < win && cnt0 < TOPK) orow[stn + s0] = 1.0f;
        if (s1 < win && cnt1 < TOPK) orow[stn + s1] = 1.0f;
    }
}

extern "C" void kernel_launch(void* const* d_in, const int* in_sizes, int n_in,
                              void* d_out, int out_size, void* d_ws, size_t ws_size,
                              hipStream_t stream)
{
    const float* X  = (const float*)d_in[0];
    const float* Wq = (const float*)d_in[1];
    const float* bq = (const float*)d_in[2];
    const float* Wk = (const float*)d_in[3];
    const float* bk = (const float*)d_in[4];
    const int* nnpg = (const int*)d_in[5];
    const int* nrel = (const int*)d_in[6];

    const int n = in_sizes[0] / NF;
    const int n_graphs = in_sizes[5];

    // Kt FIRST so its <=12B tail overread lands inside Qb (in-bounds, masked)
    float* Kt = (float*)d_ws;                 // [256][n] transposed
    float* Qb = Kt + (size_t)n * HD;          // [n][256] row-major
    float* out = (float*)d_out;

    dim3 gg(n / GROWS, 2);
    qk_gemm_kernel<<<gg, 256, 0, stream>>>(X, Wq, bq, Wk, bk, Qb, Kt, n);

    fill_zero_kernel<<<4096, 256, 0, stream>>>((float4*)out, out_size >> 2);

    attn_topk_kernel<<<n / NB, 256, 0, stream>>>(Qb, Kt, nnpg, n_graphs, nrel, out, n);
}

// Round 10
// 155.843 us; speedup vs baseline: 1.9850x; 1.1768x over previous
//
#include <hip/hip_runtime.h>

#define NF    256   // IN_F
#define HD    256   // H*D
#define NH    4
#define DH    64
#define WINS  128   // WIN
#define HALFW 64
#define TOPK  32
#define GROWS 32    // rows per gemm block (4 waves x 8 rows)

// ------------- fused Q/K projection: X[n,256] @ W[256,256] + b -------------
// grid (n/32, 2). Wave = 8 rows; lane owns cols 4l..4l+3. Per k-group of 8:
// 8 independent b128 W loads (full 1KB row per wave instr, reused by 8 rows)
// + X via wave-uniform s_loads. Row-major coalesced stores for Q AND K.
// No LDS, no barriers. Measured-best gemm structure (R6 ~20us).
__global__ __launch_bounds__(256) void qk_gemm_kernel(
    const float* __restrict__ X,
    const float* __restrict__ Wq, const float* __restrict__ bq,
    const float* __restrict__ Wk, const float* __restrict__ bk,
    float* __restrict__ Qb, float* __restrict__ Kb, int n)
{
    const int t    = threadIdx.x;
    const int wave = t >> 6;
    const int lane = t & 63;
    const bool isK = (blockIdx.y != 0);
    const float* W   = isK ? Wk : Wq;
    const float* bia = isK ? bk : bq;
    float*       Out = isK ? Kb : Qb;

    const int r0  = blockIdx.x * GROWS + wave * 8;
    const int r0s = __builtin_amdgcn_readfirstlane(r0);
    const float* Xs = X + (size_t)r0s * NF;        // scalar base -> s_load

    float4 acc[8];
#pragma unroll
    for (int r = 0; r < 8; ++r) acc[r] = make_float4(0.f, 0.f, 0.f, 0.f);

    for (int k = 0; k < NF; k += 8) {
        float4 wv[8];
#pragma unroll
        for (int u = 0; u < 8; ++u)                 // 8 independent b128 loads
            wv[u] = *(const float4*)(W + (size_t)(k + u) * HD + 4 * lane);
#pragma unroll
        for (int u = 0; u < 8; ++u) {
#pragma unroll
            for (int r = 0; r < 8; ++r) {
                float xk = Xs[r * NF + k + u];      // SGPR broadcast
                acc[r].x += xk * wv[u].x;
                acc[r].y += xk * wv[u].y;
                acc[r].z += xk * wv[u].z;
                acc[r].w += xk * wv[u].w;
            }
        }
    }

    const float4 bv = *(const float4*)(bia + 4 * lane);
#pragma unroll
    for (int r = 0; r < 8; ++r) {
        acc[r].x += bv.x; acc[r].y += bv.y; acc[r].z += bv.z; acc[r].w += bv.w;
        *(float4*)(Out + (size_t)(r0 + r) * HD + 4 * lane) = acc[r];  // coalesced
    }
}

// ---- per-node windowed attention + top-32 + fused full-row write ----
// (R3's measured-best structure: 4096 blocks, 256 threads.) One wave loads one
// full 1KB K-row per step (lane l -> float4 at l*16: fully coalesced); per-head
// dots via 16-lane shfl groups (head = lane>>4). Fused zero+ones row write.
__global__ __launch_bounds__(256) void attn_topk_kernel(
    const float* __restrict__ Q,
    const float* __restrict__ K,
    const int* __restrict__ nnpg, int n_graphs,
    const int* __restrict__ nrel,
    float* __restrict__ out, int n)
{
    const int i    = blockIdx.x;
    const int t    = threadIdx.x;
    const int wave = t >> 6;
    const int lane = t & 63;

    __shared__ float sc[NH][WINS];     // per-head scores (0 for padded slots)
    __shared__ float pr[NH][WINS];     // per-head softmax probs
    __shared__ float attnv[WINS];
    __shared__ float slotval[WINS];

    // segment bounds: tile(nnpg, R) -> cumsum -> searchsorted(right)
    int R = nrel[0];
    int total = n_graphs * R;
    int seg_start = 0, seg_end = n;
    int cum = 0;
    for (int e = 0; e < total; ++e) {
        int sz = nnpg[e % n_graphs];
        int nc = cum + sz;
        if (i < nc) { seg_start = cum; seg_end = nc; break; }
        cum = nc;
    }
    const int start = max(seg_start, i - HALFW);
    const int end   = min(seg_end,   i + HALFW);
    const int win   = end - start;            // >= 64 (segments >= 128 nodes)

    // lane's Q chunk: dims [4*lane, 4*lane+4), head = lane>>4
    const float4 q4 = *(const float4*)(Q + (size_t)i * HD + lane * 4);

    // ---- scores: wave w handles rows {w + 4j}; 8-deep independent loads ----
#pragma unroll 8
    for (int j = 0; j < 32; ++j) {
        int row = wave + 4 * j;               // 0..127
        float v = 0.f;
        if (row < win) {
            float4 k4 = *(const float4*)(K + (size_t)(start + row) * HD + lane * 4);
            v = q4.x * k4.x + q4.y * k4.y + q4.z * k4.z + q4.w * k4.w;
        }
        // sum over the 16-lane group = this head's 64 dims
        v += __shfl_xor(v, 1);
        v += __shfl_xor(v, 2);
        v += __shfl_xor(v, 4);
        v += __shfl_xor(v, 8);
        if ((lane & 15) == 0)
            sc[lane >> 4][row] = v * 0.25f;   // /sqrt(64)/tau; padded rows -> 0
    }
    __syncthreads();

    // ---- per-head softmax over full 128-slot window: wave w = head w ----
    {
        float v0 = sc[wave][lane], v1 = sc[wave][lane + 64];
        float mx = fmaxf(v0, v1);
#pragma unroll
        for (int off = 32; off > 0; off >>= 1) mx = fmaxf(mx, __shfl_xor(mx, off));
        float e0 = expf(v0 - mx), e1 = expf(v1 - mx);
        float sm = e0 + e1;
#pragma unroll
        for (int off = 32; off > 0; off >>= 1) sm += __shfl_xor(sm, off);
        pr[wave][lane]      = e0 / sm;
        pr[wave][lane + 64] = e1 / sm;
    }
    __syncthreads();

    // ---- mean over heads; invalid slots excluded from top-k ----
    if (t < WINS) {
        float a = 0.25f * (pr[0][t] + pr[1][t] + pr[2][t] + pr[3][t]);
        attnv[t] = (t < win) ? a : -1.0f;
    }
    __syncthreads();

    // ---- stable top-32 rank count (lower index wins ties, like lax.top_k) ----
    if (t < WINS) {
        float v = attnv[t];
        int cnt = 0;
#pragma unroll
        for (int j4 = 0; j4 < WINS / 4; ++j4) {
            float4 a4 = *(const float4*)&attnv[j4 * 4];
            int jb = j4 * 4;
            cnt += (a4.x > v) || (a4.x == v && (jb + 0) < t);
            cnt += (a4.y > v) || (a4.y == v && (jb + 1) < t);
            cnt += (a4.z > v) || (a4.z == v && (jb + 2) < t);
            cnt += (a4.w > v) || (a4.w == v && (jb + 3) < t);
        }
        slotval[t] = (t < win && cnt < TOPK) ? 1.0f : 0.0f;
    }
    __syncthreads();

    // ---- fused full-row write: zeros + window values, float4 stores ----
    float4* orow = (float4*)(out + (size_t)i * n);
    const int n4 = n >> 2;
    for (int c4 = t; c4 < n4; c4 += 256) {
        int c = c4 << 2;
        float4 v4 = make_float4(0.f, 0.f, 0.f, 0.f);
        if (c + 3 >= start && c < end) {
            int o = c - start;
            if (o     >= 0 && o     < WINS) v4.x = slotval[o];
            if (o + 1 >= 0 && o + 1 < WINS) v4.y = slotval[o + 1];
            if (o + 2 >= 0 && o + 2 < WINS) v4.z = slotval[o + 2];
            if (o + 3 >= 0 && o + 3 < WINS) v4.w = slotval[o + 3];
        }
        orow[c4] = v4;
    }
}

extern "C" void kernel_launch(void* const* d_in, const int* in_sizes, int n_in,
                              void* d_out, int out_size, void* d_ws, size_t ws_size,
                              hipStream_t stream)
{
    const float* X  = (const float*)d_in[0];
    const float* Wq = (const float*)d_in[1];
    const float* bq = (const float*)d_in[2];
    const float* Wk = (const float*)d_in[3];
    const float* bk = (const float*)d_in[4];
    const int* nnpg = (const int*)d_in[5];
    const int* nrel = (const int*)d_in[6];

    const int n = in_sizes[0] / NF;
    const int n_graphs = in_sizes[5];

    float* Qb = (float*)d_ws;                 // [n][256]
    float* Kb = Qb + (size_t)n * HD;          // [n][256]
    float* out = (float*)d_out;

    dim3 gg(n / GROWS, 2);
    qk_gemm_kernel<<<gg, 256, 0, stream>>>(X, Wq, bq, Wk, bk, Qb, Kb, n);

    attn_topk_kernel<<<n, 256, 0, stream>>>(Qb, Kb, nnpg, n_graphs, nrel, out, n);
}

// Round 11
// 148.259 us; speedup vs baseline: 2.0866x; 1.0512x over previous
//
#include <hip/hip_runtime.h>

#define NF    256   // IN_F
#define HD    256   // H*D
#define NH    4
#define DH    64
#define WINS  128   // WIN
#define HALFW 64
#define TOPK  32
#define GROWS 32    // rows per gemm block (4 waves x 8 rows)

// ------------- fused Q/K projection: X[n,256] @ W[256,256] + b -------------
// grid (n/32, 2). Wave = 8 rows; lane owns cols 4l..4l+3. Explicit 2-stage
// software pipeline on W: k-group g+8's eight b128 loads are issued BEFORE
// computing group g, so each group's 512-cycle FMA chain hides the ~250-cycle
// L2 latency (waitcnt becomes vmcnt(8), never a drain). X via wave-uniform
// s_loads. Row-major coalesced stores for Q and K. No LDS, no barriers.
__global__ __launch_bounds__(256) void qk_gemm_kernel(
    const float* __restrict__ X,
    const float* __restrict__ Wq, const float* __restrict__ bq,
    const float* __restrict__ Wk, const float* __restrict__ bk,
    float* __restrict__ Qb, float* __restrict__ Kb, int n)
{
    const int t    = threadIdx.x;
    const int wave = t >> 6;
    const int lane = t & 63;
    const bool isK = (blockIdx.y != 0);
    const float* W   = isK ? Wk : Wq;
    const float* bia = isK ? bk : bq;
    float*       Out = isK ? Kb : Qb;

    const int r0  = blockIdx.x * GROWS + wave * 8;
    const int r0s = __builtin_amdgcn_readfirstlane(r0);
    const float* Xs = X + (size_t)r0s * NF;        // scalar base -> s_load

    float4 acc[8];
#pragma unroll
    for (int r = 0; r < 8; ++r) acc[r] = make_float4(0.f, 0.f, 0.f, 0.f);

    float4 wA[8], wB[8];
    const float* Wl = W + 4 * lane;

    // prologue: stage k-group 0 into wA
#pragma unroll
    for (int u = 0; u < 8; ++u)
        wA[u] = *(const float4*)(Wl + (size_t)u * HD);

    for (int k = 0; k < NF; k += 16) {
        // issue next group's loads (into wB) before consuming wA
        if (k + 8 < NF) {
#pragma unroll
            for (int u = 0; u < 8; ++u)
                wB[u] = *(const float4*)(Wl + (size_t)(k + 8 + u) * HD);
        }
#pragma unroll
        for (int u = 0; u < 8; ++u) {
#pragma unroll
            for (int r = 0; r < 8; ++r) {
                float xk = Xs[r * NF + k + u];     // SGPR broadcast
                acc[r].x += xk * wA[u].x;
                acc[r].y += xk * wA[u].y;
                acc[r].z += xk * wA[u].z;
                acc[r].w += xk * wA[u].w;
            }
        }
        // issue group k+16 (into wA) before consuming wB
        if (k + 16 < NF) {
#pragma unroll
            for (int u = 0; u < 8; ++u)
                wA[u] = *(const float4*)(Wl + (size_t)(k + 16 + u) * HD);
        }
#pragma unroll
        for (int u = 0; u < 8; ++u) {
#pragma unroll
            for (int r = 0; r < 8; ++r) {
                float xk = Xs[r * NF + k + 8 + u]; // SGPR broadcast
                acc[r].x += xk * wB[u].x;
                acc[r].y += xk * wB[u].y;
                acc[r].z += xk * wB[u].z;
                acc[r].w += xk * wB[u].w;
            }
        }
    }

    const float4 bv = *(const float4*)(bia + 4 * lane);
#pragma unroll
    for (int r = 0; r < 8; ++r) {
        acc[r].x += bv.x; acc[r].y += bv.y; acc[r].z += bv.z; acc[r].w += bv.w;
        *(float4*)(Out + (size_t)(r0 + r) * HD + 4 * lane) = acc[r];  // coalesced
    }
}

// ---- per-node windowed attention + top-32 + fused full-row write ----
// (measured-best: 53.5us incl. the full 64MiB write; R3/R10 structure)
__global__ __launch_bounds__(256) void attn_topk_kernel(
    const float* __restrict__ Q,
    const float* __restrict__ K,
    const int* __restrict__ nnpg, int n_graphs,
    const int* __restrict__ nrel,
    float* __restrict__ out, int n)
{
    const int i    = blockIdx.x;
    const int t    = threadIdx.x;
    const int wave = t >> 6;
    const int lane = t & 63;

    __shared__ float sc[NH][WINS];     // per-head scores (0 for padded slots)
    __shared__ float pr[NH][WINS];     // per-head softmax probs
    __shared__ float attnv[WINS];
    __shared__ float slotval[WINS];

    // segment bounds: tile(nnpg, R) -> cumsum -> searchsorted(right)
    int R = nrel[0];
    int total = n_graphs * R;
    int seg_start = 0, seg_end = n;
    int cum = 0;
    for (int e = 0; e < total; ++e) {
        int sz = nnpg[e % n_graphs];
        int nc = cum + sz;
        if (i < nc) { seg_start = cum; seg_end = nc; break; }
        cum = nc;
    }
    const int start = max(seg_start, i - HALFW);
    const int end   = min(seg_end,   i + HALFW);
    const int win   = end - start;            // >= 64 (segments >= 128 nodes)

    // lane's Q chunk: dims [4*lane, 4*lane+4), head = lane>>4
    const float4 q4 = *(const float4*)(Q + (size_t)i * HD + lane * 4);

    // ---- scores: wave w handles rows {w + 4j}; 8-deep independent loads ----
#pragma unroll 8
    for (int j = 0; j < 32; ++j) {
        int row = wave + 4 * j;               // 0..127
        float v = 0.f;
        if (row < win) {
            float4 k4 = *(const float4*)(K + (size_t)(start + row) * HD + lane * 4);
            v = q4.x * k4.x + q4.y * k4.y + q4.z * k4.z + q4.w * k4.w;
        }
        v += __shfl_xor(v, 1);
        v += __shfl_xor(v, 2);
        v += __shfl_xor(v, 4);
        v += __shfl_xor(v, 8);
        if ((lane & 15) == 0)
            sc[lane >> 4][row] = v * 0.25f;   // /sqrt(64)/tau; padded rows -> 0
    }
    __syncthreads();

    // ---- per-head softmax over full 128-slot window: wave w = head w ----
    {
        float v0 = sc[wave][lane], v1 = sc[wave][lane + 64];
        float mx = fmaxf(v0, v1);
#pragma unroll
        for (int off = 32; off > 0; off >>= 1) mx = fmaxf(mx, __shfl_xor(mx, off));
        float e0 = expf(v0 - mx), e1 = expf(v1 - mx);
        float sm = e0 + e1;
#pragma unroll
        for (int off = 32; off > 0; off >>= 1) sm += __shfl_xor(sm, off);
        pr[wave][lane]      = e0 / sm;
        pr[wave][lane + 64] = e1 / sm;
    }
    __syncthreads();

    // ---- mean over heads; invalid slots excluded from top-k ----
    if (t < WINS) {
        float a = 0.25f * (pr[0][t] + pr[1][t] + pr[2][t] + pr[3][t]);
        attnv[t] = (t < win) ? a : -1.0f;
    }
    __syncthreads();

    // ---- stable top-32 rank count (lower index wins ties, like lax.top_k) ----
    if (t < WINS) {
        float v = attnv[t];
        int cnt = 0;
#pragma unroll
        for (int j4 = 0; j4 < WINS / 4; ++j4) {
            float4 a4 = *(const float4*)&attnv[j4 * 4];
            int jb = j4 * 4;
            cnt += (a4.x > v) || (a4.x == v && (jb + 0) < t);
            cnt += (a4.y > v) || (a4.y == v && (jb + 1) < t);
            cnt += (a4.z > v) || (a4.z == v && (jb + 2) < t);
            cnt += (a4.w > v) || (a4.w == v && (jb + 3) < t);
        }
        slotval[t] = (t < win && cnt < TOPK) ? 1.0f : 0.0f;
    }
    __syncthreads();

    // ---- fused full-row write: zeros + window values, float4 stores ----
    float4* orow = (float4*)(out + (size_t)i * n);
    const int n4 = n >> 2;
    for (int c4 = t; c4 < n4; c4 += 256) {
        int c = c4 << 2;
        float4 v4 = make_float4(0.f, 0.f, 0.f, 0.f);
        if (c + 3 >= start && c < end) {
            int o = c - start;
            if (o     >= 0 && o     < WINS) v4.x = slotval[o];
            if (o + 1 >= 0 && o + 1 < WINS) v4.y = slotval[o + 1];
            if (o + 2 >= 0 && o + 2 < WINS) v4.z = slotval[o + 2];
            if (o + 3 >= 0 && o + 3 < WINS) v4.w = slotval[o + 3];
        }
        orow[c4] = v4;
    }
}

extern "C" void kernel_launch(void* const* d_in, const int* in_sizes, int n_in,
                              void* d_out, int out_size, void* d_ws, size_t ws_size,
                              hipStream_t stream)
{
    const float* X  = (const float*)d_in[0];
    const float* Wq = (const float*)d_in[1];
    const float* bq = (const float*)d_in[2];
    const float* Wk = (const float*)d_in[3];
    const float* bk = (const float*)d_in[4];
    const int* nnpg = (const int*)d_in[5];
    const int* nrel = (const int*)d_in[6];

    const int n = in_sizes[0] / NF;
    const int n_graphs = in_sizes[5];

    float* Qb = (float*)d_ws;                 // [n][256]
    float* Kb = Qb + (size_t)n * HD;          // [n][256]
    float* out = (float*)d_out;

    dim3 gg(n / GROWS, 2);
    qk_gemm_kernel<<<gg, 256, 0, stream>>>(X, Wq, bq, Wk, bk, Qb, Kb, n);

    attn_topk_kernel<<<n, 256, 0, stream>>>(Qb, Kb, nnpg, n_graphs, nrel, out, n);
}